// Round 10
// baseline (355.268 us; speedup 1.0000x reference)
//
#include <hip/hip_runtime.h>
#include <hip/hip_bf16.h>
#include <stdint.h>

#define HDIM 1024
#define FDIM 1024
#define TTOK 2048
#define CAP  2048
#define MSZ  (1024*1024)

typedef __attribute__((ext_vector_type(8))) __bf16 bf16x8;
typedef __attribute__((ext_vector_type(4))) float  f32x4;

static __device__ __forceinline__ unsigned short f2bf(float v) {
  unsigned int u = __float_as_uint(v);
  u += 0x7FFF + ((u >> 16) & 1);   // RNE
  return (unsigned short)(u >> 16);
}

static __device__ __forceinline__ unsigned pk2(float a, float b) {
  return (unsigned)f2bf(a) | ((unsigned)f2bf(b) << 16);
}

static __device__ __forceinline__ void gload_lds16(const void* g, void* l) {
  __builtin_amdgcn_global_load_lds(
      (const __attribute__((address_space(1))) unsigned int*)g,
      (__attribute__((address_space(3))) unsigned int*)l, 16, 0, 0);
}

// ---------------- prep: x fp32->bf16 + router only (NO weight transpose) -----
__global__ __launch_bounds__(256) void k_prep(
    const float* __restrict__ x, const float* __restrict__ wg,
    unsigned short* __restrict__ xb,
    int* __restrict__ counts, int* __restrict__ tok_id, float* __restrict__ tok_w) {
  int b = blockIdx.x;
  int tid = threadIdx.x;
  if (b < 1024) {
    int i = b * 256 + tid;
    const float4* in4 = (const float4*)x;
    float4 f0 = in4[i * 2], f1 = in4[i * 2 + 1];
    uint4 v;
    v.x = pk2(f0.x, f0.y); v.y = pk2(f0.z, f0.w);
    v.z = pk2(f1.x, f1.y); v.w = pk2(f1.z, f1.w);
    *((uint4*)(xb + (size_t)i * 8)) = v;
    if (i < TTOK) { tok_id[8 * CAP + i] = i; tok_w[8 * CAP + i] = 1.0f; }
    if (i == 0) counts[8] = TTOK;
  } else {
    int t = ((b - 1024) << 2) + (tid >> 6);
    int L = tid & 63;
    const float* xr = x + (size_t)t * HDIM;
    float acc[8] = {0, 0, 0, 0, 0, 0, 0, 0};
    for (int h = L; h < HDIM; h += 64) {
      float xv = xr[h];
      const float* wr = wg + h * 8;
      #pragma unroll
      for (int e = 0; e < 8; e++) acc[e] += xv * wr[e];
    }
    #pragma unroll
    for (int e = 0; e < 8; e++) {
      float v = acc[e];
      for (int off = 32; off > 0; off >>= 1) v += __shfl_xor(v, off);
      acc[e] = v;
    }
    if (L == 0) {
      int i1 = 0; float v1 = acc[0];
      #pragma unroll
      for (int e = 1; e < 8; e++) if (acc[e] > v1) { v1 = acc[e]; i1 = e; }
      int i2 = -1; float v2 = -1e30f;
      #pragma unroll
      for (int e = 0; e < 8; e++) if (e != i1 && acc[e] > v2) { v2 = acc[e]; i2 = e; }
      float ex = __expf(v2 - v1);
      float w1 = 1.f / (1.f + ex);
      float w2 = 1.f - w1;
      int p1 = atomicAdd(&counts[i1], 1);
      tok_id[i1 * CAP + p1] = t; tok_w[i1 * CAP + p1] = w1;
      int p2 = atomicAdd(&counts[i2], 1);
      tok_id[i2 * CAP + p2] = t; tok_w[i2 * CAP + p2] = w2;
    }
  }
}

// A tiles: bf16 LDS rows [row][64], 16B chunk c of row r holds logical c^(r&7)
// (XOR swizzle, conflict-free, verified R2).  B tiles: NATIVE fp32 [k][n] rows
// staged async; additive chunk swizzle phys=(n/4 + 4*(k/8))%NC keeps fragment
// reads (8 scalar b32 per fragment, transposing) at 2-way alias = free, and
// staging's per-lane source chunk stays inside the row's contiguous segment.
// fp32->bf16 conversion happens at fragment build (same f2bf RNE as before).

// ---------------- GEMM1: act = silu(x@Wg) * (x@Wu), gathered rows ------------
// tile 128(M) x 64(N per output), BK=64; 4 waves 2x2; g and u share A.
__global__ __launch_bounds__(256, 3) void k_gemm1(
    const unsigned short* __restrict__ xb,
    const float* __restrict__ wgp, const float* __restrict__ wsg,
    const float* __restrict__ wup, const float* __restrict__ wsu,
    const int* __restrict__ counts, const int* __restrict__ tok_id,
    unsigned short* __restrict__ actb) {
  int lin = blockIdx.x;
  int e = lin >> 8;
  int r9 = lin & 255;
  int nbi = (r9 & 7) | ((r9 >> 7) << 3);   // same nb -> same lin%8 -> same XCD
  int mi  = (r9 >> 3) & 15;
  int Ne = (e == 8) ? TTOK : counts[e];
  int rb = mi << 7;
  if (rb >= Ne) return;
  int nb = nbi << 6;
  const float* wgn = (e == 8) ? wsg : wgp + (size_t)e * MSZ;  // [H][F] fp32 native
  const float* wun = (e == 8) ? wsu : wup + (size_t)e * MSZ;
  __shared__ __align__(16) unsigned short As[128 * 64];
  __shared__ __align__(16) float Bgs[64 * 64];
  __shared__ __align__(16) float Bus[64 * 64];
  int tid = threadIdx.x;
  int w = tid >> 6, L = tid & 63;
  int quad = L >> 4, lane15 = L & 15;
  int wr = w >> 1, wc = w & 1;
  int l7 = lane15 & 7;
  int sw8 = ((L & 7) ^ (L >> 3)) << 3;    // A-tile xor swizzle (bf16 elems)
  const int* tlist = tok_id + e * CAP + rb;
  int trow[4];
  #pragma unroll
  for (int r = 0; r < 4; r++) {
    int row = (w << 5) + (r << 3) + (L >> 3);
    trow[r] = (rb + row < Ne) ? tlist[row] : 0;
  }
  // B staging lane roles: per instr 4 k-rows (L>>4), phys chunk L&15
  int bkrow = (L >> 4);                   // row-sub within 4-row group
  int cph = L & 15;
  f32x4 accg[4][2], accu[4][2];
  #pragma unroll
  for (int mt = 0; mt < 4; mt++)
    #pragma unroll
    for (int nt = 0; nt < 2; nt++) {
      accg[mt][nt] = (f32x4){0.f, 0.f, 0.f, 0.f};
      accu[mt][nt] = (f32x4){0.f, 0.f, 0.f, 0.f};
    }
  for (int it = 0; it < 16; it++) {
    int k0 = it << 6;
    #pragma unroll
    for (int r = 0; r < 4; r++)
      gload_lds16(xb + (size_t)trow[r] * 1024 + k0 + sw8, As + ((w << 2) + r) * 512);
    #pragma unroll
    for (int i = 0; i < 4; i++) {
      int krow = (w << 4) + (i << 2) + bkrow;
      int clog = (cph - ((krow >> 3) << 2)) & 15;
      size_t go = (size_t)(k0 + krow) * 1024 + nb + (clog << 2);
      float* db = Bgs + (((w << 4) + (i << 2)) << 6);   // wave-uniform base
      gload_lds16(wgn + go, db);
      gload_lds16(wun + go, Bus + (((w << 4) + (i << 2)) << 6));
    }
    __syncthreads();
    #pragma unroll
    for (int s = 0; s < 2; s++) {
      bf16x8 a[4], bg[2], bu[2];
      int ch = (s << 2) + quad;
      int po = ((ch ^ l7) << 3);
      #pragma unroll
      for (int mt = 0; mt < 4; mt++)
        a[mt] = *(const bf16x8*)(As + (((wr << 6) + (mt << 4) + lane15) << 6) + po);
      int s4q = (s << 2) + quad;          // k>>3 for this fragment
      int kb = s4q << 3;
      #pragma unroll
      for (int nt = 0; nt < 2; nt++) {
        int n = (wc << 5) + (nt << 4) + lane15;
        int base = (kb << 6) + ((((n >> 2) + (s4q << 2)) & 15) << 2) + (n & 3);
        uint4 tg, tu;
        tg.x = pk2(Bgs[base],        Bgs[base + 64]);
        tg.y = pk2(Bgs[base + 128],  Bgs[base + 192]);
        tg.z = pk2(Bgs[base + 256],  Bgs[base + 320]);
        tg.w = pk2(Bgs[base + 384],  Bgs[base + 448]);
        tu.x = pk2(Bus[base],        Bus[base + 64]);
        tu.y = pk2(Bus[base + 128],  Bus[base + 192]);
        tu.z = pk2(Bus[base + 256],  Bus[base + 320]);
        tu.w = pk2(Bus[base + 384],  Bus[base + 448]);
        bg[nt] = *(bf16x8*)&tg;
        bu[nt] = *(bf16x8*)&tu;
      }
      #pragma unroll
      for (int mt = 0; mt < 4; mt++)
        #pragma unroll
        for (int nt = 0; nt < 2; nt++) {
          accg[mt][nt] = __builtin_amdgcn_mfma_f32_16x16x32_bf16(a[mt], bg[nt], accg[mt][nt], 0, 0, 0);
          accu[mt][nt] = __builtin_amdgcn_mfma_f32_16x16x32_bf16(a[mt], bu[nt], accu[mt][nt], 0, 0, 0);
        }
    }
    __syncthreads();
  }
  #pragma unroll
  for (int mt = 0; mt < 4; mt++)
    #pragma unroll
    for (int nt = 0; nt < 2; nt++)
      #pragma unroll
      for (int g = 0; g < 4; g++) {
        int r = (wr << 6) + (mt << 4) + (quad << 2) + g;
        if (rb + r < Ne) {
          float gv = accg[mt][nt][g], uv = accu[mt][nt][g];
          float av = gv / (1.f + __expf(-gv)) * uv;
          int f = nb + (wc << 5) + (nt << 4) + lane15;
          actb[(size_t)(e * CAP + rb + r) * 1024 + f] = f2bf(av);
        }
      }
}

// ---------------- GEMM2: out += w_t * (act @ Wd), atomic accumulate ----------
// tile 128x128, BK=64; 4 waves 2x2 each 64x64.  B native fp32 [f][h].
__global__ __launch_bounds__(256, 3) void k_gemm2(
    const unsigned short* __restrict__ actb,
    const float* __restrict__ wdp, const float* __restrict__ wsd,
    const int* __restrict__ counts, const int* __restrict__ tok_id,
    const float* __restrict__ tok_w, float* __restrict__ out) {
  int lin = blockIdx.x;
  int e = lin >> 7;
  int r8 = lin & 127;
  int nbi = r8 & 7;
  int mi  = r8 >> 3;
  int Ne = (e == 8) ? TTOK : counts[e];
  int rb = mi << 7;
  if (rb >= Ne) return;
  int nb = nbi << 7;
  const float* wdn = (e == 8) ? wsd : wdp + (size_t)e * MSZ;  // [F][H] fp32 native
  __shared__ __align__(16) unsigned short As[128 * 64];
  __shared__ __align__(16) float Bs[64 * 128];
  int tid = threadIdx.x;
  int w = tid >> 6, L = tid & 63;
  int quad = L >> 4, lane15 = L & 15;
  int wr = w >> 1, wc = w & 1;
  int l7 = lane15 & 7;
  int sw8 = ((L & 7) ^ (L >> 3)) << 3;
  const unsigned short* arow = actb + (size_t)(e * CAP + rb) * 1024;
  int bkrow = (L >> 5);                   // 2 rows per instr
  int cph = L & 31;                       // 32 chunks per 512B row
  f32x4 acc[4][4];
  #pragma unroll
  for (int mt = 0; mt < 4; mt++)
    #pragma unroll
    for (int nt = 0; nt < 4; nt++) acc[mt][nt] = (f32x4){0.f, 0.f, 0.f, 0.f};
  for (int it = 0; it < 16; it++) {
    int k0 = it << 6;
    #pragma unroll
    for (int r = 0; r < 4; r++) {
      int row = (w << 5) + (r << 3) + (L >> 3);
      gload_lds16(arow + (size_t)row * 1024 + k0 + sw8, As + ((w << 2) + r) * 512);
    }
    #pragma unroll
    for (int i = 0; i < 8; i++) {
      int krow = (w << 4) + (i << 1) + bkrow;
      int clog = (cph - ((krow >> 3) << 2)) & 31;
      size_t go = (size_t)(k0 + krow) * 1024 + nb + (clog << 2);
      gload_lds16(wdn + go, Bs + (((w << 4) + (i << 1)) << 7));
    }
    __syncthreads();
    #pragma unroll
    for (int s = 0; s < 2; s++) {
      bf16x8 a[4], b[4];
      int ch = (s << 2) + quad;
      int po = ((ch ^ l7) << 3);
      #pragma unroll
      for (int mt = 0; mt < 4; mt++)
        a[mt] = *(const bf16x8*)(As + (((wr << 6) + (mt << 4) + lane15) << 6) + po);
      int s4q = (s << 2) + quad;
      int kb = s4q << 3;
      #pragma unroll
      for (int nt = 0; nt < 4; nt++) {
        int n = (wc << 6) + (nt << 4) + lane15;
        int base = (kb << 7) + ((((n >> 2) + (s4q << 2)) & 31) << 2) + (n & 3);
        uint4 tb;
        tb.x = pk2(Bs[base],        Bs[base + 128]);
        tb.y = pk2(Bs[base + 256],  Bs[base + 384]);
        tb.z = pk2(Bs[base + 512],  Bs[base + 640]);
        tb.w = pk2(Bs[base + 768],  Bs[base + 896]);
        b[nt] = *(bf16x8*)&tb;
      }
      #pragma unroll
      for (int mt = 0; mt < 4; mt++)
        #pragma unroll
        for (int nt = 0; nt < 4; nt++)
          acc[mt][nt] = __builtin_amdgcn_mfma_f32_16x16x32_bf16(a[mt], b[nt], acc[mt][nt], 0, 0, 0);
    }
    __syncthreads();
  }
  #pragma unroll
  for (int mt = 0; mt < 4; mt++)
    #pragma unroll
    for (int nt = 0; nt < 4; nt++)
      #pragma unroll
      for (int g = 0; g < 4; g++) {
        int r = (wr << 6) + (mt << 4) + (quad << 2) + g;
        if (rb + r < Ne) {
          int t = tok_id[e * CAP + rb + r];
          float wt = tok_w[e * CAP + rb + r];
          int hc = nb + (wc << 6) + (nt << 4) + lane15;
          atomicAdd(out + (size_t)t * 1024 + hc, acc[mt][nt][g] * wt);
        }
      }
}

extern "C" void kernel_launch(void* const* d_in, const int* in_sizes, int n_in,
                              void* d_out, int out_size, void* d_ws, size_t ws_size,
                              hipStream_t stream) {
  (void)in_sizes; (void)n_in; (void)ws_size;
  const float* x   = (const float*)d_in[0];
  const float* wg  = (const float*)d_in[1];
  const float* wgp = (const float*)d_in[2];
  const float* wup = (const float*)d_in[3];
  const float* wdp = (const float*)d_in[4];
  const float* wsg = (const float*)d_in[5];
  const float* wsu = (const float*)d_in[6];
  const float* wsd = (const float*)d_in[7];
  float* out = (float*)d_out;
  char* ws = (char*)d_ws;
  // ws layout (bytes): xb 4194304 | actb 37748736 | tok_id 73728 | tok_w 73728
  //                    | counts 64   (~42 MiB)
  unsigned short* xb   = (unsigned short*)ws;
  unsigned short* actb = (unsigned short*)(ws + 4194304);
  int*   tok_id = (int*)(ws + 4194304 + 37748736);
  float* tok_w  = (float*)(ws + 4194304 + 37748736 + 73728);
  int*   counts = (int*)(ws + 4194304 + 37748736 + 147456);

  hipMemsetAsync(counts, 0, 64, stream);
  hipMemsetAsync(out, 0, (size_t)out_size * 4, stream);
  k_prep<<<1536, 256, 0, stream>>>(x, wg, xb, counts, tok_id, tok_w);
  k_gemm1<<<2304, 256, 0, stream>>>(xb, wgp, wsg, wup, wsu, counts, tok_id, actb);
  k_gemm2<<<1152, 256, 0, stream>>>(actb, wdp, wsd, counts, tok_id, tok_w, out);
}

// Round 11
// 304.896 us; speedup vs baseline: 1.1652x; 1.1652x over previous
//
#include <hip/hip_runtime.h>
#include <hip/hip_bf16.h>
#include <stdint.h>

#define HDIM 1024
#define FDIM 1024
#define TTOK 2048
#define CAP  2048
#define MSZ  (1024*1024)

typedef __attribute__((ext_vector_type(8))) __bf16 bf16x8;
typedef __attribute__((ext_vector_type(4))) float  f32x4;

static __device__ __forceinline__ unsigned short f2bf(float v) {
  unsigned int u = __float_as_uint(v);
  u += 0x7FFF + ((u >> 16) & 1);   // RNE
  return (unsigned short)(u >> 16);
}

static __device__ __forceinline__ unsigned pk2(float a, float b) {
  return (unsigned)f2bf(a) | ((unsigned)f2bf(b) << 16);
}

static __device__ __forceinline__ void gload_lds16(const void* g, void* l) {
  __builtin_amdgcn_global_load_lds(
      (const __attribute__((address_space(1))) unsigned int*)g,
      (__attribute__((address_space(3))) unsigned int*)l, 16, 0, 0);
}

static __device__ __forceinline__ void gload_lds4(const void* g, void* l) {
  __builtin_amdgcn_global_load_lds(
      (const __attribute__((address_space(1))) unsigned int*)g,
      (__attribute__((address_space(3))) unsigned int*)l, 4, 0, 0);
}

// ---------------- fused prep: transpose + x-cvt + router (R8 version) --------
__global__ __launch_bounds__(256) void k_prep(
    const float* __restrict__ x, const float* __restrict__ wg,
    const float* __restrict__ wgp, const float* __restrict__ wsg,
    const float* __restrict__ wup, const float* __restrict__ wsu,
    const float* __restrict__ wdp, const float* __restrict__ wsd,
    unsigned short* __restrict__ wB, unsigned short* __restrict__ xb,
    int* __restrict__ counts, int* __restrict__ tok_id, float* __restrict__ tok_w) {
  __shared__ __align__(16) float tile[64][65];
  int b = blockIdx.x;
  int tid = threadIdx.x;
  if (b < 6912) {
    int m = b >> 8;                  // 0..26
    int rblk = (b >> 4) & 15, cblk = b & 15;
    const float* src;
    if (m < 8)       src = wgp + (size_t)m * MSZ;
    else if (m == 8) src = wsg;
    else if (m < 17) src = wup + (size_t)(m - 9) * MSZ;
    else if (m == 17) src = wsu;
    else if (m < 26) src = wdp + (size_t)(m - 18) * MSZ;
    else             src = wsd;
    unsigned short* dst = wB + (size_t)m * MSZ;
    int rb = rblk << 6, cb = cblk << 6;
    int w = tid >> 6, L = tid & 63;
    #pragma unroll
    for (int i = 0; i < 16; i++) {
      int r = (w << 4) + i;
      gload_lds4(src + (size_t)(rb + r) * 1024 + cb + L, &tile[r][0]);
    }
    __syncthreads();
    int f0 = tid >> 3;               // 0..31
    int k0 = (tid & 7) << 3;         // 0..56
    #pragma unroll
    for (int half = 0; half < 2; half++) {
      int f = f0 + (half << 5);
      float e0 = tile[k0 + 0][f], e1 = tile[k0 + 1][f];
      float e2 = tile[k0 + 2][f], e3 = tile[k0 + 3][f];
      float e4 = tile[k0 + 4][f], e5 = tile[k0 + 5][f];
      float e6 = tile[k0 + 6][f], e7 = tile[k0 + 7][f];
      uint4 o;
      o.x = pk2(e0, e1); o.y = pk2(e2, e3); o.z = pk2(e4, e5); o.w = pk2(e6, e7);
      *(uint4*)(dst + (size_t)(cb + f) * 1024 + rb + k0) = o;
    }
  } else if (b < 6912 + 1024) {
    int i = (b - 6912) * 256 + tid;
    const float4* in4 = (const float4*)x;
    float4 f0 = in4[i * 2], f1 = in4[i * 2 + 1];
    uint4 v;
    v.x = pk2(f0.x, f0.y); v.y = pk2(f0.z, f0.w);
    v.z = pk2(f1.x, f1.y); v.w = pk2(f1.z, f1.w);
    *((uint4*)(xb + (size_t)i * 8)) = v;
    if (i < TTOK) { tok_id[8 * CAP + i] = i; tok_w[8 * CAP + i] = 1.0f; }
    if (i == 0) counts[8] = TTOK;
  } else {
    int t = ((b - 7936) << 2) + (tid >> 6);
    int L = tid & 63;
    const float* xr = x + (size_t)t * HDIM;
    float acc[8] = {0, 0, 0, 0, 0, 0, 0, 0};
    for (int h = L; h < HDIM; h += 64) {
      float xv = xr[h];
      const float* wr = wg + h * 8;
      #pragma unroll
      for (int e = 0; e < 8; e++) acc[e] += xv * wr[e];
    }
    #pragma unroll
    for (int e = 0; e < 8; e++) {
      float v = acc[e];
      for (int off = 32; off > 0; off >>= 1) v += __shfl_xor(v, off);
      acc[e] = v;
    }
    if (L == 0) {
      int i1 = 0; float v1 = acc[0];
      #pragma unroll
      for (int e = 1; e < 8; e++) if (acc[e] > v1) { v1 = acc[e]; i1 = e; }
      int i2 = -1; float v2 = -1e30f;
      #pragma unroll
      for (int e = 0; e < 8; e++) if (e != i1 && acc[e] > v2) { v2 = acc[e]; i2 = e; }
      float ex = __expf(v2 - v1);
      float w1 = 1.f / (1.f + ex);
      float w2 = 1.f - w1;
      int p1 = atomicAdd(&counts[i1], 1);
      tok_id[i1 * CAP + p1] = t; tok_w[i1 * CAP + p1] = w1;
      int p2 = atomicAdd(&counts[i2], 1);
      tok_id[i2 * CAP + p2] = t; tok_w[i2 * CAP + p2] = w2;
    }
  }
}

// GEMM K-loops: AITER-style pipeline.  Double-buffered LDS; per iter: issue
// next stage's 8 global_load_lds, s_waitcnt vmcnt(8) (waits ONLY for current
// stage; next stays in flight across the barrier), raw s_barrier (no implicit
// drain), MFMA from current stage, raw s_barrier (buffer-reuse guard: every
// wave's ds_reads were consumed by pre-barrier MFMAs).  vmcnt(0) only at the
// final iteration.  LDS swizzle: 16B chunk c of row r holds logical c^(r&7)
// (conflict-free, verified R2).  1D grids decoded so same-B-tile blocks share
// lin%8 -> same XCD L2.

#define PIPE_SYNC(LAST) \
  { if (LAST) asm volatile("s_waitcnt vmcnt(0)" ::: "memory"); \
    else      asm volatile("s_waitcnt vmcnt(8)" ::: "memory"); \
    asm volatile("s_barrier" ::: "memory"); }
#define PIPE_TAIL() asm volatile("s_barrier" ::: "memory");

// ---------------- GEMM1: act = silu(x@Wg) * (x@Wu), gathered rows ------------
// tile 128(M) x 64(N per output), BK=64; 4 waves 2x2; g and u share A.
__global__ __launch_bounds__(256, 2) void k_gemm1(
    const unsigned short* __restrict__ xb, const unsigned short* __restrict__ wB,
    const int* __restrict__ counts, const int* __restrict__ tok_id,
    unsigned short* __restrict__ actb) {
  int lin = blockIdx.x;
  int e = lin >> 8;
  int r9 = lin & 255;
  int nbi = (r9 & 7) | ((r9 >> 7) << 3);
  int mi  = (r9 >> 3) & 15;
  int Ne = (e == 8) ? TTOK : counts[e];
  int rb = mi << 7;
  if (rb >= Ne) return;
  int nb = nbi << 6;
  const unsigned short* wg = wB + (size_t)e * MSZ;        // [F][H] bf16
  const unsigned short* wu = wB + (size_t)(9 + e) * MSZ;  // [F][H] bf16
  __shared__ __align__(16) unsigned short As[2][128 * 64];
  __shared__ __align__(16) unsigned short Bgs[2][64 * 64];
  __shared__ __align__(16) unsigned short Bus[2][64 * 64];
  int tid = threadIdx.x;
  int w = tid >> 6, L = tid & 63;
  int quad = L >> 4, lane15 = L & 15;
  int wr = w >> 1, wc = w & 1;
  int l7 = lane15 & 7;
  int sw8 = ((L & 7) ^ (L >> 3)) << 3;
  const int* tlist = tok_id + e * CAP + rb;
  int trow[4];
  #pragma unroll
  for (int r = 0; r < 4; r++) {
    int row = (w << 5) + (r << 3) + (L >> 3);
    trow[r] = (rb + row < Ne) ? tlist[row] : 0;
  }
  int frg = (((w << 1)) << 3) + (L >> 3);       // base B row staged by this lane (j=0)
  f32x4 accg[4][2], accu[4][2];
  #pragma unroll
  for (int mt = 0; mt < 4; mt++)
    #pragma unroll
    for (int nt = 0; nt < 2; nt++) {
      accg[mt][nt] = (f32x4){0.f, 0.f, 0.f, 0.f};
      accu[mt][nt] = (f32x4){0.f, 0.f, 0.f, 0.f};
    }
  // preload stage 0
  #pragma unroll
  for (int r = 0; r < 4; r++)
    gload_lds16(xb + (size_t)trow[r] * 1024 + sw8, As[0] + ((w << 2) + r) * 512);
  #pragma unroll
  for (int r = 0; r < 2; r++) {
    int fr = (((w << 1) + r) << 3) + (L >> 3);
    size_t go = (size_t)(nb + fr) * 1024 + sw8;
    gload_lds16(wg + go, Bgs[0] + ((w << 1) + r) * 512);
    gload_lds16(wu + go, Bus[0] + ((w << 1) + r) * 512);
  }
  for (int it = 0; it < 16; it++) {
    int cur = it & 1;
    int last = (it == 15);
    if (!last) {
      int k1 = (it + 1) << 6;
      int nxt = cur ^ 1;
      #pragma unroll
      for (int r = 0; r < 4; r++)
        gload_lds16(xb + (size_t)trow[r] * 1024 + k1 + sw8, As[nxt] + ((w << 2) + r) * 512);
      #pragma unroll
      for (int r = 0; r < 2; r++) {
        int fr = (((w << 1) + r) << 3) + (L >> 3);
        size_t go = (size_t)(nb + fr) * 1024 + k1 + sw8;
        gload_lds16(wg + go, Bgs[nxt] + ((w << 1) + r) * 512);
        gload_lds16(wu + go, Bus[nxt] + ((w << 1) + r) * 512);
      }
    }
    PIPE_SYNC(last)
    #pragma unroll
    for (int s = 0; s < 2; s++) {
      bf16x8 a[4], bg[2], bu[2];
      int ch = (s << 2) + quad;
      int po = ((ch ^ l7) << 3);
      #pragma unroll
      for (int mt = 0; mt < 4; mt++)
        a[mt] = *(const bf16x8*)(As[cur] + (((wr << 6) + (mt << 4) + lane15) << 6) + po);
      #pragma unroll
      for (int nt = 0; nt < 2; nt++) {
        int rrow = ((wc << 5) + (nt << 4) + lane15) << 6;
        bg[nt] = *(const bf16x8*)(Bgs[cur] + rrow + po);
        bu[nt] = *(const bf16x8*)(Bus[cur] + rrow + po);
      }
      #pragma unroll
      for (int mt = 0; mt < 4; mt++)
        #pragma unroll
        for (int nt = 0; nt < 2; nt++) {
          accg[mt][nt] = __builtin_amdgcn_mfma_f32_16x16x32_bf16(a[mt], bg[nt], accg[mt][nt], 0, 0, 0);
          accu[mt][nt] = __builtin_amdgcn_mfma_f32_16x16x32_bf16(a[mt], bu[nt], accu[mt][nt], 0, 0, 0);
        }
    }
    PIPE_TAIL()
  }
  (void)frg;
  #pragma unroll
  for (int mt = 0; mt < 4; mt++)
    #pragma unroll
    for (int nt = 0; nt < 2; nt++)
      #pragma unroll
      for (int g = 0; g < 4; g++) {
        int r = (wr << 6) + (mt << 4) + (quad << 2) + g;
        if (rb + r < Ne) {
          float gv = accg[mt][nt][g], uv = accu[mt][nt][g];
          float av = gv / (1.f + __expf(-gv)) * uv;
          int f = nb + (wc << 5) + (nt << 4) + lane15;
          actb[(size_t)(e * CAP + rb + r) * 1024 + f] = f2bf(av);
        }
      }
}

// ---------------- GEMM2: out += w_t * (act @ Wd), atomic accumulate ----------
// tile 128x128, BK=64; 4 waves 2x2 each 64x64.
__global__ __launch_bounds__(256, 2) void k_gemm2(
    const unsigned short* __restrict__ actb, const unsigned short* __restrict__ wB,
    const int* __restrict__ counts, const int* __restrict__ tok_id,
    const float* __restrict__ tok_w, float* __restrict__ out) {
  int lin = blockIdx.x;
  int e = lin >> 7;
  int r8 = lin & 127;
  int nbi = r8 & 7;
  int mi  = r8 >> 3;
  int Ne = (e == 8) ? TTOK : counts[e];
  int rb = mi << 7;
  if (rb >= Ne) return;
  int nb = nbi << 7;
  const unsigned short* wd = wB + (size_t)(18 + e) * MSZ;  // [H][F] bf16
  __shared__ __align__(16) unsigned short As[2][128 * 64];
  __shared__ __align__(16) unsigned short Bs[2][128 * 64];
  int tid = threadIdx.x;
  int w = tid >> 6, L = tid & 63;
  int quad = L >> 4, lane15 = L & 15;
  int wr = w >> 1, wc = w & 1;
  int l7 = lane15 & 7;
  int sw8 = ((L & 7) ^ (L >> 3)) << 3;
  const unsigned short* arow = actb + (size_t)(e * CAP + rb) * 1024;
  f32x4 acc[4][4];
  #pragma unroll
  for (int mt = 0; mt < 4; mt++)
    #pragma unroll
    for (int nt = 0; nt < 4; nt++) acc[mt][nt] = (f32x4){0.f, 0.f, 0.f, 0.f};
  // preload stage 0
  #pragma unroll
  for (int r = 0; r < 4; r++) {
    int row = (w << 5) + (r << 3) + (L >> 3);
    gload_lds16(arow + (size_t)row * 1024 + sw8, As[0] + ((w << 2) + r) * 512);
    gload_lds16(wd + (size_t)(nb + row) * 1024 + sw8, Bs[0] + ((w << 2) + r) * 512);
  }
  for (int it = 0; it < 16; it++) {
    int cur = it & 1;
    int last = (it == 15);
    if (!last) {
      int k1 = (it + 1) << 6;
      int nxt = cur ^ 1;
      #pragma unroll
      for (int r = 0; r < 4; r++) {
        int row = (w << 5) + (r << 3) + (L >> 3);
        gload_lds16(arow + (size_t)row * 1024 + k1 + sw8, As[nxt] + ((w << 2) + r) * 512);
        gload_lds16(wd + (size_t)(nb + row) * 1024 + k1 + sw8, Bs[nxt] + ((w << 2) + r) * 512);
      }
    }
    PIPE_SYNC(last)
    #pragma unroll
    for (int s = 0; s < 2; s++) {
      bf16x8 a[4], b[4];
      int ch = (s << 2) + quad;
      int po = ((ch ^ l7) << 3);
      #pragma unroll
      for (int mt = 0; mt < 4; mt++)
        a[mt] = *(const bf16x8*)(As[cur] + (((wr << 6) + (mt << 4) + lane15) << 6) + po);
      #pragma unroll
      for (int nt = 0; nt < 4; nt++)
        b[nt] = *(const bf16x8*)(Bs[cur] + (((wc << 6) + (nt << 4) + lane15) << 6) + po);
      #pragma unroll
      for (int mt = 0; mt < 4; mt++)
        #pragma unroll
        for (int nt = 0; nt < 4; nt++)
          acc[mt][nt] = __builtin_amdgcn_mfma_f32_16x16x32_bf16(a[mt], b[nt], acc[mt][nt], 0, 0, 0);
    }
    PIPE_TAIL()
  }
  #pragma unroll
  for (int mt = 0; mt < 4; mt++)
    #pragma unroll
    for (int nt = 0; nt < 4; nt++)
      #pragma unroll
      for (int g = 0; g < 4; g++) {
        int r = (wr << 6) + (mt << 4) + (quad << 2) + g;
        if (rb + r < Ne) {
          int t = tok_id[e * CAP + rb + r];
          float wt = tok_w[e * CAP + rb + r];
          int hc = nb + (wc << 6) + (nt << 4) + lane15;
          atomicAdd(out + (size_t)t * 1024 + hc, acc[mt][nt][g] * wt);
        }
      }
}

extern "C" void kernel_launch(void* const* d_in, const int* in_sizes, int n_in,
                              void* d_out, int out_size, void* d_ws, size_t ws_size,
                              hipStream_t stream) {
  (void)in_sizes; (void)n_in; (void)ws_size;
  const float* x   = (const float*)d_in[0];
  const float* wg  = (const float*)d_in[1];
  const float* wgp = (const float*)d_in[2];
  const float* wup = (const float*)d_in[3];
  const float* wdp = (const float*)d_in[4];
  const float* wsg = (const float*)d_in[5];
  const float* wsu = (const float*)d_in[6];
  const float* wsd = (const float*)d_in[7];
  float* out = (float*)d_out;
  char* ws = (char*)d_ws;
  // ws layout (bytes): wB 27*MSZ*2 = 56623104 | xb 4194304 | actb 37748736
  //                    | tok_id 73728 | tok_w 73728 | counts 64   (~94.1 MiB)
  unsigned short* wB   = (unsigned short*)ws;
  unsigned short* xb   = (unsigned short*)(ws + 56623104);
  unsigned short* actb = (unsigned short*)(ws + 56623104 + 4194304);
  int*   tok_id = (int*)(ws + 56623104 + 4194304 + 37748736);
  float* tok_w  = (float*)(ws + 56623104 + 4194304 + 37748736 + 73728);
  int*   counts = (int*)(ws + 56623104 + 4194304 + 37748736 + 147456);

  hipMemsetAsync(counts, 0, 64, stream);
  hipMemsetAsync(out, 0, (size_t)out_size * 4, stream);
  k_prep<<<8448, 256, 0, stream>>>(x, wg, wgp, wsg, wup, wsu, wdp, wsd,
                                   wB, xb, counts, tok_id, tok_w);
  k_gemm1<<<2304, 256, 0, stream>>>(xb, wB, counts, tok_id, actb);
  k_gemm2<<<1152, 256, 0, stream>>>(actb, wB, counts, tok_id, tok_w, out);
}